// Round 15
// baseline (139.994 us; speedup 1.0000x reference)
//
#include <hip/hip_runtime.h>

constexpr int Bn = 32;
constexpr int Cn = 128;
constexpr int Mn = 4000;
constexpr int Gn = 4;
constexpr int Dn = 32;   // C / G
constexpr float GN_EPS = 1e-5f;
constexpr float IN_EPS = 1e-3f;
constexpr float BN_EPS = 1e-5f;

typedef __attribute__((ext_vector_type(8))) short bf16x8;
typedef __attribute__((ext_vector_type(4))) float f32x4;
typedef __attribute__((ext_vector_type(16))) float f32x16;

__device__ __forceinline__ float bf2f(ushort u) {
    union { unsigned int u; float f; } v;
    v.u = ((unsigned int)u) << 16;
    return v.f;
}
__device__ __forceinline__ ushort f2bf(float f) {
    union { float f; unsigned int u; } v;
    v.f = f;
    unsigned int r = v.u + 0x7FFFu + ((v.u >> 16) & 1u);
    return (ushort)(r >> 16);
}

// ---------------------------------------------------------------------------
// prep_w3: three fp32 W[128][128] -> bf16, one launch
// ---------------------------------------------------------------------------
__global__ void prep_w3(const float* __restrict__ w0, const float* __restrict__ w1,
                        const float* __restrict__ w2, ushort* __restrict__ wb) {
    const int i = blockIdx.x * 256 + threadIdx.x;   // 49152 total
    const int which = i >> 14;
    const int off = i & 16383;
    const float v = (which == 0) ? w0[off] : (which == 1) ? w1[off] : w2[off];
    wb[i] = f2bf(v);
}

// ---------------------------------------------------------------------------
// prep_xt: x [b][c][m] fp32 -> xt [b][m][c] bf16.
// Tile 32m x 128c: reads 128B/row coalesced, writes FULL 256B rows.
// ---------------------------------------------------------------------------
__launch_bounds__(256)
__global__ void prep_xt(const float* __restrict__ x, ushort* __restrict__ xt) {
    __shared__ float tl[128 * 33];   // [c][m], 16896 B
    const int mb = blockIdx.x * 32, b = blockIdx.y;
    const int tid = threadIdx.x;
    const int mi = tid & 31, cg = tid >> 5;
#pragma unroll
    for (int p = 0; p < 16; ++p) {
        const int ci = cg + 8 * p;                  // 0..127
        tl[ci * 33 + mi] = x[((size_t)b * Cn + ci) * Mn + mb + mi];
    }
    __syncthreads();
#pragma unroll
    for (int q = 0; q < 2; ++q) {
        const int row = (tid >> 4) + 16 * q;        // 0..31
        const int c8 = (tid & 15) * 8;
        bf16x8 v;
#pragma unroll
        for (int e = 0; e < 8; ++e)
            v[e] = (short)f2bf(tl[(c8 + e) * 33 + row]);
        *(bf16x8*)(xt + ((size_t)b * Mn + mb + row) * Cn + c8) = v;
    }
}

// ---------------------------------------------------------------------------
// FUSED M0 + covariance + ALL channel stats, 4 m-tiles per block.
// ---------------------------------------------------------------------------
constexpr int WPAD = 136;   // ushort stride for W rows
constexpr int EP0  = 132;   // ushort stride for El tile

__launch_bounds__(256, 2)
__global__ void mgemm0_cov(const ushort* __restrict__ Wb,
                           const ushort* __restrict__ src,      // xt
                           ushort* __restrict__ dst_bf,         // featt
                           float* __restrict__ sf, float* __restrict__ sf2,
                           float* __restrict__ sfxp,
                           float* __restrict__ sxp, float* __restrict__ sx2p,
                           float* __restrict__ covp)
{
    __shared__ ushort Wl[128 * WPAD];   // W, persists across tiles
    __shared__ ushort El[64 * EP0];     // featt tile; red aliases after loop
    const int b = blockIdx.y;
    const int mb0 = blockIdx.x * 256;
    const int tid = threadIdx.x;
    const int wv = tid >> 6, l = tid & 63;
    const int li = l & 15, lg = l >> 4;

#pragma unroll
    for (int p = 0; p < 8; ++p) {
        const int u = tid + 256 * p;
        const int o = u >> 4, c8 = (u & 15) * 8;
        *(bf16x8*)&Wl[o * WPAD + c8] = *(const bf16x8*)(Wb + (size_t)o * 128 + c8);
    }
    __syncthreads();

    f32x16 cacc;
#pragma unroll
    for (int i = 0; i < 16; ++i) cacc[i] = 0.f;
    float s1a[8] = {}, s2a[8] = {}, s3a[8] = {}, s4a[8] = {}, s5a[8] = {};

    const int c8s = (tid & 15) * 8;
    const int cg = wv * 32 + (l & 31);
    const int kb8 = (l >> 5) * 8;

#pragma unroll 1
    for (int t = 0; t < 4; ++t) {
        const int mb = mb0 + t * 64;
        const int ma = mb + wv * 16 + li;
        const bool mok = ma < Mn;
        const size_t qrow = ((size_t)b * Mn + (mok ? ma : (Mn - 1))) * Cn;

        bf16x8 fr[4];
#pragma unroll
        for (int kb = 0; kb < 4; ++kb)
            fr[kb] = *(const bf16x8*)(src + qrow + kb * 32 + 8 * lg);

        f32x4 acc[8];
#pragma unroll
        for (int j = 0; j < 8; ++j)
#pragma unroll
            for (int r = 0; r < 4; ++r) acc[j][r] = 0.f;

#pragma unroll
        for (int kb = 0; kb < 4; ++kb) {
            const int cl = kb * 32 + 8 * lg;
#pragma unroll
            for (int j = 0; j < 8; ++j) {
                const bf16x8 bj = *(const bf16x8*)&Wl[(j * 16 + li) * WPAD + cl];
                acc[j] = __builtin_amdgcn_mfma_f32_16x16x32_bf16(fr[kb], bj, acc[j], 0, 0, 0);
            }
        }

        __syncthreads();
#pragma unroll
        for (int j = 0; j < 8; ++j) {
            const int o = j * 16 + li;
#pragma unroll
            for (int r = 0; r < 4; ++r) {
                const int ml = wv * 16 + lg * 4 + r;
                El[ml * EP0 + o] = (mb + ml < Mn) ? f2bf(acc[j][r]) : (ushort)0;
            }
        }
        __syncthreads();

#pragma unroll
        for (int p = 0; p < 4; ++p) {
            const int row = (tid >> 4) + 16 * p;
            const int m = mb + row;
            const bf16x8 v8 = *(const bf16x8*)&El[row * EP0 + c8s];
            if (m < Mn) {
                const size_t q = ((size_t)b * Mn + m) * Cn + c8s;
                *(bf16x8*)(dst_bf + q) = v8;
                const bf16x8 x8 = *(const bf16x8*)(src + q);
#pragma unroll
                for (int e = 0; e < 8; ++e) {
                    const float f = bf2f((ushort)v8[e]);
                    const float xv = bf2f((ushort)x8[e]);
                    s1a[e] += f;
                    s2a[e] = fmaf(f, f, s2a[e]);
                    s3a[e] = fmaf(f, xv, s3a[e]);
                    s4a[e] += xv;
                    s5a[e] = fmaf(xv, xv, s5a[e]);
                }
            }
        }

#pragma unroll
        for (int ks = 0; ks < 4; ++ks) {
            bf16x8 fgr;
#pragma unroll
            for (int e = 0; e < 8; ++e)
                fgr[e] = (short)El[(ks * 16 + kb8 + e) * EP0 + cg];
            cacc = __builtin_amdgcn_mfma_f32_32x32x16_bf16(fgr, fgr, cacc, 0, 0, 0);
        }
    }

    __syncthreads();
#pragma unroll
    for (int e = 0; e < 8; ++e) {
        s1a[e] += __shfl_xor(s1a[e], 16); s1a[e] += __shfl_xor(s1a[e], 32);
        s2a[e] += __shfl_xor(s2a[e], 16); s2a[e] += __shfl_xor(s2a[e], 32);
        s3a[e] += __shfl_xor(s3a[e], 16); s3a[e] += __shfl_xor(s3a[e], 32);
        s4a[e] += __shfl_xor(s4a[e], 16); s4a[e] += __shfl_xor(s4a[e], 32);
        s5a[e] += __shfl_xor(s5a[e], 16); s5a[e] += __shfl_xor(s5a[e], 32);
    }
    float* red = (float*)El;
    if (l < 16) {
#pragma unroll
        for (int e = 0; e < 8; ++e) {
            red[(wv * 16 + l) * 40 + e]      = s1a[e];
            red[(wv * 16 + l) * 40 + 8 + e]  = s2a[e];
            red[(wv * 16 + l) * 40 + 16 + e] = s3a[e];
            red[(wv * 16 + l) * 40 + 24 + e] = s4a[e];
            red[(wv * 16 + l) * 40 + 32 + e] = s5a[e];
        }
    }
    __syncthreads();
    if (tid < 128) {
        const int oc = tid >> 3, e = tid & 7;
        const int o = oc * 8 + e;
        float t1 = 0.f, t2 = 0.f, t3 = 0.f, t4 = 0.f, t5 = 0.f;
#pragma unroll
        for (int w = 0; w < 4; ++w) {
            t1 += red[(w * 16 + oc) * 40 + e];
            t2 += red[(w * 16 + oc) * 40 + 8 + e];
            t3 += red[(w * 16 + oc) * 40 + 16 + e];
            t4 += red[(w * 16 + oc) * 40 + 24 + e];
            t5 += red[(w * 16 + oc) * 40 + 32 + e];
        }
        atomicAdd(&sf[b * Cn + o], t1);
        atomicAdd(&sf2[b * Cn + o], t2);
        atomicAdd(&sfxp[b * Cn + o], t3);
        atomicAdd(&sxp[b * Cn + o], t4);
        atomicAdd(&sx2p[b * Cn + o], t5);
    }
    float* cvb = covp + (size_t)(b * Gn + wv) * (Dn * Dn);
#pragma unroll
    for (int reg = 0; reg < 16; ++reg) {
        const int i = (reg & 3) + 8 * (reg >> 2) + 4 * (l >> 5);
        const int j = l & 31;
        atomicAdd(&cvb[i * Dn + j], cacc[reg]);
    }
}

// ---------------------------------------------------------------------------
// MFMA GEMM for MODE 1/2 (64m x 64o, o-split grid).
// h2t layout is [b][o-half][m][64] so MODE 1 writes FULL 256B lines and
// MODE 2 reads contiguous half-slices (no write amplification).
// MODE 1: h2t = relu(tA*(s*f+x)+tB) @ W^T + bias; per-(b,o) stats.
// MODE 2: out = relu(tA*h2+tB) @ W^T + bias + y (y recomputed from featt/xt)
// ---------------------------------------------------------------------------
constexpr int EPAD = 68;    // ushort stride for 64-wide epilogue tiles

template <int MODE>
__launch_bounds__(256, 8)
__global__ void mgemm_kernel(const ushort* __restrict__ Wb,
                             const ushort* __restrict__ src,
                             const ushort* __restrict__ xsrc,
                             ushort* __restrict__ dst_bf,
                             float* __restrict__ dst_f32,
                             const float* __restrict__ bias,
                             const float* __restrict__ sarr,
                             const float* __restrict__ tA,
                             const float* __restrict__ tB,
                             const float* __restrict__ Ayc,
                             const float* __restrict__ Byc,
                             const ushort* __restrict__ yfeat,
                             const ushort* __restrict__ yxt,
                             float* __restrict__ sum1,
                             float* __restrict__ sum2)
{
    __shared__ ushort Wl[64 * WPAD];      // 17408 B; epilogues alias this
    __shared__ float coefLDS[640];
    const int b = blockIdx.z;
    const int obh = blockIdx.y;           // o-half index
    const int ob = obh * 64;
    const int mb = blockIdx.x * 64;
    const int tid = threadIdx.x;
    const int wv = tid >> 6, l = tid & 63;
    const int li = l & 15, lg = l >> 4;

#pragma unroll
    for (int p = 0; p < 4; ++p) {
        const int u = tid + 256 * p;
        const int row = u >> 4, c8 = (u & 15) * 8;
        *(bf16x8*)&Wl[row * WPAD + c8] = *(const bf16x8*)(Wb + (size_t)(ob + row) * 128 + c8);
    }
    {
        const int ncoef = (MODE == 1) ? 384 : 640;
        for (int idx = tid; idx < ncoef; idx += 256) {
            const int arr = idx >> 7, c = idx & 127;
            float v;
            switch (arr) {
                case 0: v = tA[b * Cn + c]; break;
                case 1: v = tB[b * Cn + c]; break;
                case 2: v = sarr[b * Cn + c]; break;
                case 3: v = Ayc[b * Cn + c]; break;
                default: v = Byc[b * Cn + c]; break;
            }
            coefLDS[idx] = v;
        }
    }
    __syncthreads();

    f32x4 acc[4];
#pragma unroll
    for (int j = 0; j < 4; ++j)
#pragma unroll
        for (int r = 0; r < 4; ++r) acc[j][r] = 0.f;

    const int ma = mb + wv * 16 + li;
    const bool mok = ma < Mn;
    const int mc = mok ? ma : (Mn - 1);
    const size_t qrow = ((size_t)b * Mn + mc) * Cn;   // [b][m][128] layouts

    bf16x8 fr[4], xr[4];
#pragma unroll
    for (int kb = 0; kb < 4; ++kb) {
        if (MODE == 1) {
            const int cl = kb * 32 + 8 * lg;
            fr[kb] = *(const bf16x8*)(src + qrow + cl);
            xr[kb] = *(const bf16x8*)(xsrc + qrow + cl);
        } else {
            // src = h2t in [b][2][m][64] layout; cl = kb*32+8*lg maps to
            // half = kb>>1, in-half offset = (kb&1)*32 + 8*lg
            const size_t q2 = (((size_t)b * 2 + (kb >> 1)) * Mn + mc) * 64 + (kb & 1) * 32 + 8 * lg;
            fr[kb] = *(const bf16x8*)(src + q2);
        }
    }

#pragma unroll
    for (int kb = 0; kb < 4; ++kb) {
        const int cl = kb * 32 + 8 * lg;
        bf16x8 af;
        if (MODE == 1) {
            const float4 a0 = *(const float4*)&coefLDS[0 + cl];
            const float4 a1 = *(const float4*)&coefLDS[0 + cl + 4];
            const float4 b0 = *(const float4*)&coefLDS[128 + cl];
            const float4 b1 = *(const float4*)&coefLDS[128 + cl + 4];
            const float4 s0 = *(const float4*)&coefLDS[256 + cl];
            const float4 s1 = *(const float4*)&coefLDS[256 + cl + 4];
            const float tAv[8] = {a0.x,a0.y,a0.z,a0.w,a1.x,a1.y,a1.z,a1.w};
            const float tBv[8] = {b0.x,b0.y,b0.z,b0.w,b1.x,b1.y,b1.z,b1.w};
            const float svv[8] = {s0.x,s0.y,s0.z,s0.w,s1.x,s1.y,s1.z,s1.w};
#pragma unroll
            for (int e = 0; e < 8; ++e) {
                const float vv = fmaf(svv[e], bf2f((ushort)fr[kb][e]), bf2f((ushort)xr[kb][e]));
                af[e] = (short)f2bf(fmaxf(fmaf(tAv[e], vv, tBv[e]), 0.f));
            }
        } else {
            const float4 a0 = *(const float4*)&coefLDS[0 + cl];
            const float4 a1 = *(const float4*)&coefLDS[0 + cl + 4];
            const float4 b0 = *(const float4*)&coefLDS[128 + cl];
            const float4 b1 = *(const float4*)&coefLDS[128 + cl + 4];
            const float tAv[8] = {a0.x,a0.y,a0.z,a0.w,a1.x,a1.y,a1.z,a1.w};
            const float tBv[8] = {b0.x,b0.y,b0.z,b0.w,b1.x,b1.y,b1.z,b1.w};
#pragma unroll
            for (int e = 0; e < 8; ++e)
                af[e] = (short)f2bf(fmaxf(fmaf(tAv[e], bf2f((ushort)fr[kb][e]), tBv[e]), 0.f));
        }
#pragma unroll
        for (int j = 0; j < 4; ++j) {
            const bf16x8 bj = *(const bf16x8*)&Wl[(j * 16 + li) * WPAD + cl];
            acc[j] = __builtin_amdgcn_mfma_f32_16x16x32_bf16(af, bj, acc[j], 0, 0, 0);
        }
    }

    // ---------------- epilogues ----------------
    if constexpr (MODE == 1) {
        __syncthreads();
        ushort* El = Wl;
#pragma unroll
        for (int j = 0; j < 4; ++j) {
            const int o = j * 16 + li;
            const float bv = bias[ob + o];
#pragma unroll
            for (int r = 0; r < 4; ++r) {
                const int ml = wv * 16 + lg * 4 + r;
                El[ml * EPAD + o] = f2bf(acc[j][r] + bv);
            }
        }
        __syncthreads();
        const int c8l = (tid & 7) * 8;
        float s1a[8] = {}, s2a[8] = {};
#pragma unroll
        for (int p = 0; p < 2; ++p) {
            const int row = (tid >> 3) + 32 * p;
            const int m = mb + row;
            const bf16x8 v8 = *(const bf16x8*)&El[row * EPAD + c8l];
            if (m < Mn) {
                // h2t layout [b][2][m][64]: full-line writes per block
                *(bf16x8*)(dst_bf + (((size_t)b * 2 + obh) * Mn + m) * 64 + c8l) = v8;
#pragma unroll
                for (int e = 0; e < 8; ++e) {
                    const float f = bf2f((ushort)v8[e]);
                    s1a[e] += f;
                    s2a[e] = fmaf(f, f, s2a[e]);
                }
            }
        }
#pragma unroll
        for (int e = 0; e < 8; ++e) {
            s1a[e] += __shfl_xor(s1a[e], 8);  s2a[e] += __shfl_xor(s2a[e], 8);
            s1a[e] += __shfl_xor(s1a[e], 16); s2a[e] += __shfl_xor(s2a[e], 16);
            s1a[e] += __shfl_xor(s1a[e], 32); s2a[e] += __shfl_xor(s2a[e], 32);
        }
        __syncthreads();
        float* red = coefLDS;
        if (l < 8) {
#pragma unroll
            for (int e = 0; e < 8; ++e) {
                red[wv * 128 + l * 8 + e] = s1a[e];
                red[wv * 128 + 64 + l * 8 + e] = s2a[e];
            }
        }
        __syncthreads();
        if (tid < 128) {
            const int which = tid >> 6, ol = tid & 63;
            const float v = red[0 * 128 + which * 64 + ol] + red[1 * 128 + which * 64 + ol] +
                            red[2 * 128 + which * 64 + ol] + red[3 * 128 + which * 64 + ol];
            atomicAdd((which ? sum2 : sum1) + b * Cn + ob + ol, v);
        }
    } else {
        // MODE 2: recompute y = Ay*(s*featt+xt)+By at output coords, stage
        // into El, fold bias+y, transpose 32-o halves, store fp32 [o][m].
        __syncthreads();
        ushort* El = Wl;
        float* TR = (float*)(Wl + 64 * EPAD);
        const int c8l = (tid & 7) * 8;
#pragma unroll
        for (int p = 0; p < 2; ++p) {
            const int row = (tid >> 3) + 32 * p;
            bf16x8 yv;
#pragma unroll
            for (int e = 0; e < 8; ++e) yv[e] = 0;
            if (mb + row < Mn) {
                const size_t q = ((size_t)b * Mn + mb + row) * Cn + ob + c8l;
                const bf16x8 f8 = *(const bf16x8*)(yfeat + q);
                const bf16x8 x8 = *(const bf16x8*)(yxt + q);
#pragma unroll
                for (int e = 0; e < 8; ++e) {
                    const int c = ob + c8l + e;
                    const float vv = fmaf(coefLDS[256 + c], bf2f((ushort)f8[e]), bf2f((ushort)x8[e]));
                    yv[e] = (short)f2bf(fmaf(coefLDS[384 + c], vv, coefLDS[512 + c]));
                }
            }
            *(bf16x8*)&El[row * EPAD + c8l] = yv;
        }
        __syncthreads();
#pragma unroll
        for (int j = 0; j < 4; ++j) {
            const int o = j * 16 + li;
            const float bv = bias[ob + o];
#pragma unroll
            for (int r = 0; r < 4; ++r) {
                const int ml = wv * 16 + lg * 4 + r;
                acc[j][r] += bv + bf2f(El[ml * EPAD + o]);
            }
        }
#pragma unroll
        for (int h = 0; h < 2; ++h) {
#pragma unroll
            for (int jj = 0; jj < 2; ++jj) {
                const int j = h * 2 + jj;
#pragma unroll
                for (int r = 0; r < 4; ++r) {
                    const int ml = wv * 16 + lg * 4 + r;
                    TR[(jj * 16 + li) * EPAD + ml] = acc[j][r];
                }
            }
            __syncthreads();
#pragma unroll
            for (int p = 0; p < 2; ++p) {
                const int u = tid + 256 * p;
                const int ol = u >> 4, q = u & 15;
                const int m = mb + 4 * q;
                if (m < Mn) {
                    const f32x4 v = *(const f32x4*)&TR[ol * EPAD + 4 * q];
                    *(f32x4*)(dst_f32 + ((size_t)b * Cn + ob + h * 32 + ol) * Mn + m) = v;
                }
            }
            __syncthreads();
        }
    }
}

// ---------------------------------------------------------------------------
// Newton-Schulz sqrtm per (b,g) 32x32 + row-mean -> s[b,c]
// ---------------------------------------------------------------------------
__device__ __forceinline__ void mm32(float (*A)[33], float (*Bm)[33],
                                     float (*O)[33], int ei, int ej0)
{
    float a0 = 0.f, a1 = 0.f, a2 = 0.f, a3 = 0.f;
#pragma unroll
    for (int k = 0; k < 32; ++k) {
        const float a = A[ei][k];
        a0 = fmaf(a, Bm[k][ej0 + 0], a0);
        a1 = fmaf(a, Bm[k][ej0 + 1], a1);
        a2 = fmaf(a, Bm[k][ej0 + 2], a2);
        a3 = fmaf(a, Bm[k][ej0 + 3], a3);
    }
    O[ei][ej0 + 0] = a0;
    O[ei][ej0 + 1] = a1;
    O[ei][ej0 + 2] = a2;
    O[ei][ej0 + 3] = a3;
    __syncthreads();
}

__launch_bounds__(256)
__global__ void sqrtm_kernel(const float* __restrict__ cov,
                             const float* __restrict__ sf,
                             float* __restrict__ sout)
{
    __shared__ float b0[32][33], b1[32][33], b2[32][33], b3[32][33];
    __shared__ float sh_tr, sh_scale;
    const int bg = blockIdx.x;
    const int b = bg >> 2, g = bg & 3;
    const int tid = threadIdx.x;
    const int ei = (tid * 4) >> 5, ej0 = (tid * 4) & 31;
    const float* cp = cov + (size_t)bg * (Dn * Dn);
    const float* fs = sf + b * Cn + g * Dn;
    const float invM = 1.f / Mn;
    const float mi = fs[ei] * invM;
#pragma unroll
    for (int q = 0; q < 4; ++q)
        b0[ei][ej0 + q] = cp[ei * Dn + ej0 + q] * invM - mi * (fs[ej0 + q] * invM);
    __syncthreads();
    if (tid < 32) {
        float d = b0[tid][tid];
#pragma unroll
        for (int dd = 1; dd < 32; dd <<= 1) d += __shfl_xor(d, dd);
        if (tid == 0) { sh_tr = d; sh_scale = 0.5f * sqrtf(d); }
    }
    __syncthreads();
    const float invtr = 1.f / sh_tr;
#pragma unroll
    for (int q = 0; q < 4; ++q) {
        const float an = b0[ei][ej0 + q] * invtr;
        b0[ei][ej0 + q] = an;
        b1[ei][ej0 + q] = ((ei == ej0 + q) ? 1.5f : 0.f) - 0.5f * an;
    }
    __syncthreads();
    mm32(b0, b1, b2, ei, ej0);  // Y = An @ ZY
    float (*pY)[33] = b2;
    float (*pZ)[33] = b1;
    float (*pF1)[33] = b0;
    float (*pF2)[33] = b3;
#pragma unroll 1
    for (int it = 0; it < 3; ++it) {
        mm32(pZ, pY, pF1, ei, ej0);
#pragma unroll
        for (int q = 0; q < 4; ++q)
            pF1[ei][ej0 + q] = ((ei == ej0 + q) ? 1.5f : 0.f) - 0.5f * pF1[ei][ej0 + q];
        __syncthreads();
        mm32(pY, pF1, pF2, ei, ej0);
        mm32(pF1, pZ, pY, ei, ej0);
        float (*oldZ)[33] = pZ;
        pZ = pY;
        pY = pF2;
        pF2 = oldZ;
    }
    mm32(pZ, pY, pF1, ei, ej0);
#pragma unroll
    for (int q = 0; q < 4; ++q)
        pF1[ei][ej0 + q] = ((ei == ej0 + q) ? 3.f : 0.f) - pF1[ei][ej0 + q];
    __syncthreads();
    mm32(pY, pF1, pF2, ei, ej0);
    if (tid < 32) {
        float t = 0.f;
#pragma unroll
        for (int i = 0; i < 32; ++i) t += pF2[i][tid];
        sout[b * Cn + g * Dn + tid] = t * sh_scale * (1.f / Dn);
    }
}

// ---------------------------------------------------------------------------
// coef1 / coef2 (analytic affine propagation)
// ---------------------------------------------------------------------------
__launch_bounds__(1024)
__global__ void coef1_kernel(const float* __restrict__ sf, const float* __restrict__ sf2,
                             const float* __restrict__ sfx, const float* __restrict__ sx,
                             const float* __restrict__ sx2, const float* __restrict__ s,
                             const float* __restrict__ gng, const float* __restrict__ gnb,
                             const float* __restrict__ bn1g, const float* __restrict__ bn1b,
                             float* __restrict__ Ay, float* __restrict__ By,
                             float* __restrict__ Ah, float* __restrict__ Bh)
{
    __shared__ float smv[Bn * Cn];
    __shared__ float sm2[Bn * Cn];
    __shared__ float smu[Bn * Gn], srs[Bn * Gn];
    __shared__ float sV[Cn];
    const int tid = threadIdx.x;
    const float invM = 1.f / Mn;
    for (int p = tid; p < Bn * Cn; p += 1024) {
        const float sv = s[p];
        smv[p] = fmaf(sv, sf[p], sx[p]) * invM;
        sm2[p] = (sv * sv * sf2[p] + 2.f * sv * sfx[p] + sx2[p]) * invM;
    }
    __syncthreads();
    if (tid < Bn * Gn) {
        const int base = tid * Dn;
        float mu = 0.f, e2 = 0.f;
        for (int c = 0; c < Dn; ++c) { mu += smv[base + c]; e2 += sm2[base + c]; }
        mu *= (1.f / Dn); e2 *= (1.f / Dn);
        smu[tid] = mu;
        srs[tid] = rsqrtf(e2 - mu * mu + GN_EPS);
    }
    __syncthreads();
    for (int p = tid; p < Bn * Cn; p += 1024) {
        const int c = p & (Cn - 1);
        const int bg = p >> 5;
        const float ay = srs[bg] * gng[c];
        const float mv = smv[p];
        sm2[p] = ay * ay * (sm2[p] - mv * mv);
    }
    __syncthreads();
    if (tid < Cn) {
        float V = 0.f;
        for (int b = 0; b < Bn; ++b) {
            const float vy = sm2[b * Cn + tid];
            V += vy / (vy + IN_EPS);
        }
        sV[tid] = V * (1.f / Bn);
    }
    __syncthreads();
    for (int p = tid; p < Bn * Cn; p += 1024) {
        const int c = p & (Cn - 1);
        const int bg = p >> 5;
        const float ay = srs[bg] * gng[c];
        const float mv = smv[p];
        const float by = gnb[c] - smu[bg] * ay;
        const float rsin = rsqrtf(sm2[p] + IN_EPS);
        const float ah = ay * rsin * rsqrtf(sV[c] + BN_EPS) * bn1g[c];
        const float bh = bn1b[c] - ah * mv;
        Ay[p] = ay; By[p] = by; Ah[p] = ah; Bh[p] = bh;
    }
}

__launch_bounds__(1024)
__global__ void coef2_kernel(const float* __restrict__ sum1, const float* __restrict__ sum2,
                             const float* __restrict__ bn2g, const float* __restrict__ bn2b,
                             float* __restrict__ A2, float* __restrict__ B2)
{
    __shared__ float svar[Bn * Cn];
    __shared__ float sV[Cn];
    const int tid = threadIdx.x;
    const float invM = 1.f / Mn;
    for (int p = tid; p < Bn * Cn; p += 1024) {
        const float mu = sum1[p] * invM;
        svar[p] = sum2[p] * invM - mu * mu;
    }
    __syncthreads();
    if (tid < Cn) {
        float V = 0.f;
        for (int b = 0; b < Bn; ++b) {
            const float v = svar[b * Cn + tid];
            V += v / (v + IN_EPS);
        }
        sV[tid] = V * (1.f / Bn);
    }
    __syncthreads();
    for (int p = tid; p < Bn * Cn; p += 1024) {
        const int c = p & (Cn - 1);
        const float mu = sum1[p] * invM;
        const float a2 = rsqrtf(svar[p] + IN_EPS) * rsqrtf(sV[c] + BN_EPS) * bn2g[c];
        A2[p] = a2;
        B2[p] = bn2b[c] - a2 * mu;
    }
}

// ---------------------------------------------------------------------------
extern "C" void kernel_launch(void* const* d_in, const int* in_sizes, int n_in,
                              void* d_out, int out_size, void* d_ws, size_t ws_size,
                              hipStream_t stream)
{
    const float* x      = (const float*)d_in[0];
    const float* w_lin  = (const float*)d_in[1];
    const float* gn_g   = (const float*)d_in[2];
    const float* gn_b   = (const float*)d_in[3];
    const float* bn1g   = (const float*)d_in[4];
    const float* bn1b   = (const float*)d_in[5];
    const float* conv1w = (const float*)d_in[6];
    const float* conv1b = (const float*)d_in[7];
    const float* bn2g   = (const float*)d_in[8];
    const float* bn2b   = (const float*)d_in[9];
    const float* conv2w = (const float*)d_in[10];
    const float* conv2b = (const float*)d_in[11];
    float* out = (float*)d_out;

    const size_t TS = (size_t)Bn * Mn * Cn;
    ushort* xt    = (ushort*)d_ws;
    ushort* featt = xt + TS;
    ushort* h2t   = featt + TS;       // [b][2][m][64] layout, same size
    ushort* wb1   = h2t + TS;
    ushort* wb2   = wb1 + Cn * Cn;
    ushort* wb3   = wb2 + Cn * Cn;
    float*  fbase = (float*)(wb3 + Cn * Cn);
    float* sarr = fbase;
    float* Ay   = sarr + Bn * Cn;
    float* By   = Ay + Bn * Cn;
    float* Ah   = By + Bn * Cn;
    float* Bh   = Ah + Bn * Cn;
    float* A2   = Bh + Bn * Cn;
    float* B2   = A2 + Bn * Cn;
    float* zbase = B2 + Bn * Cn;
    float* cov  = zbase;
    float* sf   = cov + Bn * Gn * Dn * Dn;
    float* sf2  = sf + Bn * Cn;
    float* sfx  = sf2 + Bn * Cn;
    float* sx   = sfx + Bn * Cn;
    float* sx2  = sx + Bn * Cn;
    float* sum1 = sx2 + Bn * Cn;
    float* sum2 = sum1 + Bn * Cn;
    const size_t zfloats = (size_t)Bn * Gn * Dn * Dn + 7 * Bn * Cn;

    hipMemsetAsync(zbase, 0, zfloats * sizeof(float), stream);

    prep_w3<<<dim3(192), 256, 0, stream>>>(w_lin, conv1w, conv2w, wb1);
    prep_xt<<<dim3(Mn / 32, Bn), 256, 0, stream>>>(x, xt);

    // 1) FUSED: featt = xt @ W1^T + all channel stats + covariance
    mgemm0_cov<<<dim3((Mn + 255) / 256, Bn), 256, 0, stream>>>(
        wb1, xt, featt, sf, sf2, sfx, sx, sx2, cov);

    // 2) Newton-Schulz sqrtm -> s
    sqrtm_kernel<<<Bn * Gn, 256, 0, stream>>>(cov, sf, sarr);

    // 3) affine coefficients (GN + first IN/BN/ReLU)
    coef1_kernel<<<1, 1024, 0, stream>>>(sf, sf2, sfx, sx, sx2, sarr,
                                         gn_g, gn_b, bn1g, bn1b, Ay, By, Ah, Bh);

    const dim3 ggrid((Mn + 63) / 64, 2, Bn);   // 63 x 2 x 32 = 4032 blocks

    // 4) h2t = relu(Ah*(s*featt+xt)+Bh) @ W2^T + b1, stats (full-line writes)
    mgemm_kernel<1><<<ggrid, 256, 0, stream>>>(
        wb2, featt, xt, h2t, nullptr, conv1b, sarr, Ah, Bh,
        nullptr, nullptr, nullptr, nullptr, sum1, sum2);

    // 5) second-stage affine coefficients
    coef2_kernel<<<1, 1024, 0, stream>>>(sum1, sum2, bn2g, bn2b, A2, B2);

    // 6) out = relu(A2*h2t+B2) @ W3^T + b2 + y (y recomputed from featt/xt)
    mgemm_kernel<2><<<ggrid, 256, 0, stream>>>(
        wb3, h2t, nullptr, nullptr, out, conv2b, sarr, A2, B2,
        Ay, By, featt, xt, nullptr, nullptr);
}

// Round 16
// 137.575 us; speedup vs baseline: 1.0176x; 1.0176x over previous
//
#include <hip/hip_runtime.h>

constexpr int Bn = 32;
constexpr int Cn = 128;
constexpr int Mn = 4000;
constexpr int Gn = 4;
constexpr int Dn = 32;   // C / G
constexpr float GN_EPS = 1e-5f;
constexpr float IN_EPS = 1e-3f;
constexpr float BN_EPS = 1e-5f;

typedef __attribute__((ext_vector_type(8))) short bf16x8;
typedef __attribute__((ext_vector_type(4))) float f32x4;
typedef __attribute__((ext_vector_type(16))) float f32x16;

__device__ __forceinline__ float bf2f(ushort u) {
    union { unsigned int u; float f; } v;
    v.u = ((unsigned int)u) << 16;
    return v.f;
}
__device__ __forceinline__ ushort f2bf(float f) {
    union { float f; unsigned int u; } v;
    v.f = f;
    unsigned int r = v.u + 0x7FFFu + ((v.u >> 16) & 1u);
    return (ushort)(r >> 16);
}

// ---------------------------------------------------------------------------
// prep_w3: three fp32 W[128][128] -> bf16, PLUS zero the accumulator region
// (replaces a pathologically slow 41us hipMemsetAsync fill kernel).
// grid 192 x 256 = 49152 threads; 39936 float4 zeros cover 159744 floats.
// ---------------------------------------------------------------------------
__global__ void prep_w3(const float* __restrict__ w0, const float* __restrict__ w1,
                        const float* __restrict__ w2, ushort* __restrict__ wb,
                        float* __restrict__ zbase, int zquads) {
    const int i = blockIdx.x * 256 + threadIdx.x;   // 49152 total
    const int which = i >> 14;
    const int off = i & 16383;
    const float v = (which == 0) ? w0[off] : (which == 1) ? w1[off] : w2[off];
    wb[i] = f2bf(v);
    if (i < zquads) {
        f32x4 z;
        z[0] = 0.f; z[1] = 0.f; z[2] = 0.f; z[3] = 0.f;
        *(f32x4*)(zbase + (size_t)i * 4) = z;
    }
}

// ---------------------------------------------------------------------------
// prep_xt: x [b][c][m] fp32 -> xt [b][m][c] bf16.
// Tile 32m x 128c: reads 128B/row coalesced, writes FULL 256B rows.
// ---------------------------------------------------------------------------
__launch_bounds__(256)
__global__ void prep_xt(const float* __restrict__ x, ushort* __restrict__ xt) {
    __shared__ float tl[128 * 33];   // [c][m], 16896 B
    const int mb = blockIdx.x * 32, b = blockIdx.y;
    const int tid = threadIdx.x;
    const int mi = tid & 31, cg = tid >> 5;
#pragma unroll
    for (int p = 0; p < 16; ++p) {
        const int ci = cg + 8 * p;                  // 0..127
        tl[ci * 33 + mi] = x[((size_t)b * Cn + ci) * Mn + mb + mi];
    }
    __syncthreads();
#pragma unroll
    for (int q = 0; q < 2; ++q) {
        const int row = (tid >> 4) + 16 * q;        // 0..31
        const int c8 = (tid & 15) * 8;
        bf16x8 v;
#pragma unroll
        for (int e = 0; e < 8; ++e)
            v[e] = (short)f2bf(tl[(c8 + e) * 33 + row]);
        *(bf16x8*)(xt + ((size_t)b * Mn + mb + row) * Cn + c8) = v;
    }
}

// ---------------------------------------------------------------------------
// FUSED M0 + covariance + ALL channel stats, 4 m-tiles per block.
// ---------------------------------------------------------------------------
constexpr int WPAD = 136;   // ushort stride for W rows
constexpr int EP0  = 132;   // ushort stride for El tile

__launch_bounds__(256, 2)
__global__ void mgemm0_cov(const ushort* __restrict__ Wb,
                           const ushort* __restrict__ src,      // xt
                           ushort* __restrict__ dst_bf,         // featt
                           float* __restrict__ sf, float* __restrict__ sf2,
                           float* __restrict__ sfxp,
                           float* __restrict__ sxp, float* __restrict__ sx2p,
                           float* __restrict__ covp)
{
    __shared__ ushort Wl[128 * WPAD];   // W, persists across tiles
    __shared__ ushort El[64 * EP0];     // featt tile; red aliases after loop
    const int b = blockIdx.y;
    const int mb0 = blockIdx.x * 256;
    const int tid = threadIdx.x;
    const int wv = tid >> 6, l = tid & 63;
    const int li = l & 15, lg = l >> 4;

#pragma unroll
    for (int p = 0; p < 8; ++p) {
        const int u = tid + 256 * p;
        const int o = u >> 4, c8 = (u & 15) * 8;
        *(bf16x8*)&Wl[o * WPAD + c8] = *(const bf16x8*)(Wb + (size_t)o * 128 + c8);
    }
    __syncthreads();

    f32x16 cacc;
#pragma unroll
    for (int i = 0; i < 16; ++i) cacc[i] = 0.f;
    float s1a[8] = {}, s2a[8] = {}, s3a[8] = {}, s4a[8] = {}, s5a[8] = {};

    const int c8s = (tid & 15) * 8;
    const int cg = wv * 32 + (l & 31);
    const int kb8 = (l >> 5) * 8;

#pragma unroll 1
    for (int t = 0; t < 4; ++t) {
        const int mb = mb0 + t * 64;
        const int ma = mb + wv * 16 + li;
        const bool mok = ma < Mn;
        const size_t qrow = ((size_t)b * Mn + (mok ? ma : (Mn - 1))) * Cn;

        bf16x8 fr[4];
#pragma unroll
        for (int kb = 0; kb < 4; ++kb)
            fr[kb] = *(const bf16x8*)(src + qrow + kb * 32 + 8 * lg);

        f32x4 acc[8];
#pragma unroll
        for (int j = 0; j < 8; ++j)
#pragma unroll
            for (int r = 0; r < 4; ++r) acc[j][r] = 0.f;

#pragma unroll
        for (int kb = 0; kb < 4; ++kb) {
            const int cl = kb * 32 + 8 * lg;
#pragma unroll
            for (int j = 0; j < 8; ++j) {
                const bf16x8 bj = *(const bf16x8*)&Wl[(j * 16 + li) * WPAD + cl];
                acc[j] = __builtin_amdgcn_mfma_f32_16x16x32_bf16(fr[kb], bj, acc[j], 0, 0, 0);
            }
        }

        __syncthreads();
#pragma unroll
        for (int j = 0; j < 8; ++j) {
            const int o = j * 16 + li;
#pragma unroll
            for (int r = 0; r < 4; ++r) {
                const int ml = wv * 16 + lg * 4 + r;
                El[ml * EP0 + o] = (mb + ml < Mn) ? f2bf(acc[j][r]) : (ushort)0;
            }
        }
        __syncthreads();

#pragma unroll
        for (int p = 0; p < 4; ++p) {
            const int row = (tid >> 4) + 16 * p;
            const int m = mb + row;
            const bf16x8 v8 = *(const bf16x8*)&El[row * EP0 + c8s];
            if (m < Mn) {
                const size_t q = ((size_t)b * Mn + m) * Cn + c8s;
                *(bf16x8*)(dst_bf + q) = v8;
                const bf16x8 x8 = *(const bf16x8*)(src + q);
#pragma unroll
                for (int e = 0; e < 8; ++e) {
                    const float f = bf2f((ushort)v8[e]);
                    const float xv = bf2f((ushort)x8[e]);
                    s1a[e] += f;
                    s2a[e] = fmaf(f, f, s2a[e]);
                    s3a[e] = fmaf(f, xv, s3a[e]);
                    s4a[e] += xv;
                    s5a[e] = fmaf(xv, xv, s5a[e]);
                }
            }
        }

#pragma unroll
        for (int ks = 0; ks < 4; ++ks) {
            bf16x8 fgr;
#pragma unroll
            for (int e = 0; e < 8; ++e)
                fgr[e] = (short)El[(ks * 16 + kb8 + e) * EP0 + cg];
            cacc = __builtin_amdgcn_mfma_f32_32x32x16_bf16(fgr, fgr, cacc, 0, 0, 0);
        }
    }

    __syncthreads();
#pragma unroll
    for (int e = 0; e < 8; ++e) {
        s1a[e] += __shfl_xor(s1a[e], 16); s1a[e] += __shfl_xor(s1a[e], 32);
        s2a[e] += __shfl_xor(s2a[e], 16); s2a[e] += __shfl_xor(s2a[e], 32);
        s3a[e] += __shfl_xor(s3a[e], 16); s3a[e] += __shfl_xor(s3a[e], 32);
        s4a[e] += __shfl_xor(s4a[e], 16); s4a[e] += __shfl_xor(s4a[e], 32);
        s5a[e] += __shfl_xor(s5a[e], 16); s5a[e] += __shfl_xor(s5a[e], 32);
    }
    float* red = (float*)El;
    if (l < 16) {
#pragma unroll
        for (int e = 0; e < 8; ++e) {
            red[(wv * 16 + l) * 40 + e]      = s1a[e];
            red[(wv * 16 + l) * 40 + 8 + e]  = s2a[e];
            red[(wv * 16 + l) * 40 + 16 + e] = s3a[e];
            red[(wv * 16 + l) * 40 + 24 + e] = s4a[e];
            red[(wv * 16 + l) * 40 + 32 + e] = s5a[e];
        }
    }
    __syncthreads();
    if (tid < 128) {
        const int oc = tid >> 3, e = tid & 7;
        const int o = oc * 8 + e;
        float t1 = 0.f, t2 = 0.f, t3 = 0.f, t4 = 0.f, t5 = 0.f;
#pragma unroll
        for (int w = 0; w < 4; ++w) {
            t1 += red[(w * 16 + oc) * 40 + e];
            t2 += red[(w * 16 + oc) * 40 + 8 + e];
            t3 += red[(w * 16 + oc) * 40 + 16 + e];
            t4 += red[(w * 16 + oc) * 40 + 24 + e];
            t5 += red[(w * 16 + oc) * 40 + 32 + e];
        }
        atomicAdd(&sf[b * Cn + o], t1);
        atomicAdd(&sf2[b * Cn + o], t2);
        atomicAdd(&sfxp[b * Cn + o], t3);
        atomicAdd(&sxp[b * Cn + o], t4);
        atomicAdd(&sx2p[b * Cn + o], t5);
    }
    float* cvb = covp + (size_t)(b * Gn + wv) * (Dn * Dn);
#pragma unroll
    for (int reg = 0; reg < 16; ++reg) {
        const int i = (reg & 3) + 8 * (reg >> 2) + 4 * (l >> 5);
        const int j = l & 31;
        atomicAdd(&cvb[i * Dn + j], cacc[reg]);
    }
}

// ---------------------------------------------------------------------------
// MFMA GEMM for MODE 1/2 (64m x 64o, o-split grid).
// h2t layout is [b][o-half][m][64] (full-line writes, no amplification).
// ---------------------------------------------------------------------------
constexpr int EPAD = 68;    // ushort stride for 64-wide epilogue tiles

template <int MODE>
__launch_bounds__(256, 8)
__global__ void mgemm_kernel(const ushort* __restrict__ Wb,
                             const ushort* __restrict__ src,
                             const ushort* __restrict__ xsrc,
                             ushort* __restrict__ dst_bf,
                             float* __restrict__ dst_f32,
                             const float* __restrict__ bias,
                             const float* __restrict__ sarr,
                             const float* __restrict__ tA,
                             const float* __restrict__ tB,
                             const float* __restrict__ Ayc,
                             const float* __restrict__ Byc,
                             const ushort* __restrict__ yfeat,
                             const ushort* __restrict__ yxt,
                             float* __restrict__ sum1,
                             float* __restrict__ sum2)
{
    __shared__ ushort Wl[64 * WPAD];      // 17408 B; epilogues alias this
    __shared__ float coefLDS[640];
    const int b = blockIdx.z;
    const int obh = blockIdx.y;           // o-half index
    const int ob = obh * 64;
    const int mb = blockIdx.x * 64;
    const int tid = threadIdx.x;
    const int wv = tid >> 6, l = tid & 63;
    const int li = l & 15, lg = l >> 4;

#pragma unroll
    for (int p = 0; p < 4; ++p) {
        const int u = tid + 256 * p;
        const int row = u >> 4, c8 = (u & 15) * 8;
        *(bf16x8*)&Wl[row * WPAD + c8] = *(const bf16x8*)(Wb + (size_t)(ob + row) * 128 + c8);
    }
    {
        const int ncoef = (MODE == 1) ? 384 : 640;
        for (int idx = tid; idx < ncoef; idx += 256) {
            const int arr = idx >> 7, c = idx & 127;
            float v;
            switch (arr) {
                case 0: v = tA[b * Cn + c]; break;
                case 1: v = tB[b * Cn + c]; break;
                case 2: v = sarr[b * Cn + c]; break;
                case 3: v = Ayc[b * Cn + c]; break;
                default: v = Byc[b * Cn + c]; break;
            }
            coefLDS[idx] = v;
        }
    }
    __syncthreads();

    f32x4 acc[4];
#pragma unroll
    for (int j = 0; j < 4; ++j)
#pragma unroll
        for (int r = 0; r < 4; ++r) acc[j][r] = 0.f;

    const int ma = mb + wv * 16 + li;
    const bool mok = ma < Mn;
    const int mc = mok ? ma : (Mn - 1);
    const size_t qrow = ((size_t)b * Mn + mc) * Cn;   // [b][m][128] layouts

    bf16x8 fr[4], xr[4];
#pragma unroll
    for (int kb = 0; kb < 4; ++kb) {
        if (MODE == 1) {
            const int cl = kb * 32 + 8 * lg;
            fr[kb] = *(const bf16x8*)(src + qrow + cl);
            xr[kb] = *(const bf16x8*)(xsrc + qrow + cl);
        } else {
            const size_t q2 = (((size_t)b * 2 + (kb >> 1)) * Mn + mc) * 64 + (kb & 1) * 32 + 8 * lg;
            fr[kb] = *(const bf16x8*)(src + q2);
        }
    }

#pragma unroll
    for (int kb = 0; kb < 4; ++kb) {
        const int cl = kb * 32 + 8 * lg;
        bf16x8 af;
        if (MODE == 1) {
            const float4 a0 = *(const float4*)&coefLDS[0 + cl];
            const float4 a1 = *(const float4*)&coefLDS[0 + cl + 4];
            const float4 b0 = *(const float4*)&coefLDS[128 + cl];
            const float4 b1 = *(const float4*)&coefLDS[128 + cl + 4];
            const float4 s0 = *(const float4*)&coefLDS[256 + cl];
            const float4 s1 = *(const float4*)&coefLDS[256 + cl + 4];
            const float tAv[8] = {a0.x,a0.y,a0.z,a0.w,a1.x,a1.y,a1.z,a1.w};
            const float tBv[8] = {b0.x,b0.y,b0.z,b0.w,b1.x,b1.y,b1.z,b1.w};
            const float svv[8] = {s0.x,s0.y,s0.z,s0.w,s1.x,s1.y,s1.z,s1.w};
#pragma unroll
            for (int e = 0; e < 8; ++e) {
                const float vv = fmaf(svv[e], bf2f((ushort)fr[kb][e]), bf2f((ushort)xr[kb][e]));
                af[e] = (short)f2bf(fmaxf(fmaf(tAv[e], vv, tBv[e]), 0.f));
            }
        } else {
            const float4 a0 = *(const float4*)&coefLDS[0 + cl];
            const float4 a1 = *(const float4*)&coefLDS[0 + cl + 4];
            const float4 b0 = *(const float4*)&coefLDS[128 + cl];
            const float4 b1 = *(const float4*)&coefLDS[128 + cl + 4];
            const float tAv[8] = {a0.x,a0.y,a0.z,a0.w,a1.x,a1.y,a1.z,a1.w};
            const float tBv[8] = {b0.x,b0.y,b0.z,b0.w,b1.x,b1.y,b1.z,b1.w};
#pragma unroll
            for (int e = 0; e < 8; ++e)
                af[e] = (short)f2bf(fmaxf(fmaf(tAv[e], bf2f((ushort)fr[kb][e]), tBv[e]), 0.f));
        }
#pragma unroll
        for (int j = 0; j < 4; ++j) {
            const bf16x8 bj = *(const bf16x8*)&Wl[(j * 16 + li) * WPAD + cl];
            acc[j] = __builtin_amdgcn_mfma_f32_16x16x32_bf16(af, bj, acc[j], 0, 0, 0);
        }
    }

    // ---------------- epilogues ----------------
    if constexpr (MODE == 1) {
        __syncthreads();
        ushort* El = Wl;
#pragma unroll
        for (int j = 0; j < 4; ++j) {
            const int o = j * 16 + li;
            const float bv = bias[ob + o];
#pragma unroll
            for (int r = 0; r < 4; ++r) {
                const int ml = wv * 16 + lg * 4 + r;
                El[ml * EPAD + o] = f2bf(acc[j][r] + bv);
            }
        }
        __syncthreads();
        const int c8l = (tid & 7) * 8;
        float s1a[8] = {}, s2a[8] = {};
#pragma unroll
        for (int p = 0; p < 2; ++p) {
            const int row = (tid >> 3) + 32 * p;
            const int m = mb + row;
            const bf16x8 v8 = *(const bf16x8*)&El[row * EPAD + c8l];
            if (m < Mn) {
                *(bf16x8*)(dst_bf + (((size_t)b * 2 + obh) * Mn + m) * 64 + c8l) = v8;
#pragma unroll
                for (int e = 0; e < 8; ++e) {
                    const float f = bf2f((ushort)v8[e]);
                    s1a[e] += f;
                    s2a[e] = fmaf(f, f, s2a[e]);
                }
            }
        }
#pragma unroll
        for (int e = 0; e < 8; ++e) {
            s1a[e] += __shfl_xor(s1a[e], 8);  s2a[e] += __shfl_xor(s2a[e], 8);
            s1a[e] += __shfl_xor(s1a[e], 16); s2a[e] += __shfl_xor(s2a[e], 16);
            s1a[e] += __shfl_xor(s1a[e], 32); s2a[e] += __shfl_xor(s2a[e], 32);
        }
        __syncthreads();
        float* red = coefLDS;
        if (l < 8) {
#pragma unroll
            for (int e = 0; e < 8; ++e) {
                red[wv * 128 + l * 8 + e] = s1a[e];
                red[wv * 128 + 64 + l * 8 + e] = s2a[e];
            }
        }
        __syncthreads();
        if (tid < 128) {
            const int which = tid >> 6, ol = tid & 63;
            const float v = red[0 * 128 + which * 64 + ol] + red[1 * 128 + which * 64 + ol] +
                            red[2 * 128 + which * 64 + ol] + red[3 * 128 + which * 64 + ol];
            atomicAdd((which ? sum2 : sum1) + b * Cn + ob + ol, v);
        }
    } else {
        __syncthreads();
        ushort* El = Wl;
        float* TR = (float*)(Wl + 64 * EPAD);
        const int c8l = (tid & 7) * 8;
#pragma unroll
        for (int p = 0; p < 2; ++p) {
            const int row = (tid >> 3) + 32 * p;
            bf16x8 yv;
#pragma unroll
            for (int e = 0; e < 8; ++e) yv[e] = 0;
            if (mb + row < Mn) {
                const size_t q = ((size_t)b * Mn + mb + row) * Cn + ob + c8l;
                const bf16x8 f8 = *(const bf16x8*)(yfeat + q);
                const bf16x8 x8 = *(const bf16x8*)(yxt + q);
#pragma unroll
                for (int e = 0; e < 8; ++e) {
                    const int c = ob + c8l + e;
                    const float vv = fmaf(coefLDS[256 + c], bf2f((ushort)f8[e]), bf2f((ushort)x8[e]));
                    yv[e] = (short)f2bf(fmaf(coefLDS[384 + c], vv, coefLDS[512 + c]));
                }
            }
            *(bf16x8*)&El[row * EPAD + c8l] = yv;
        }
        __syncthreads();
#pragma unroll
        for (int j = 0; j < 4; ++j) {
            const int o = j * 16 + li;
            const float bv = bias[ob + o];
#pragma unroll
            for (int r = 0; r < 4; ++r) {
                const int ml = wv * 16 + lg * 4 + r;
                acc[j][r] += bv + bf2f(El[ml * EPAD + o]);
            }
        }
#pragma unroll
        for (int h = 0; h < 2; ++h) {
#pragma unroll
            for (int jj = 0; jj < 2; ++jj) {
                const int j = h * 2 + jj;
#pragma unroll
                for (int r = 0; r < 4; ++r) {
                    const int ml = wv * 16 + lg * 4 + r;
                    TR[(jj * 16 + li) * EPAD + ml] = acc[j][r];
                }
            }
            __syncthreads();
#pragma unroll
            for (int p = 0; p < 2; ++p) {
                const int u = tid + 256 * p;
                const int ol = u >> 4, q = u & 15;
                const int m = mb + 4 * q;
                if (m < Mn) {
                    const f32x4 v = *(const f32x4*)&TR[ol * EPAD + 4 * q];
                    *(f32x4*)(dst_f32 + ((size_t)b * Cn + ob + h * 32 + ol) * Mn + m) = v;
                }
            }
            __syncthreads();
        }
    }
}

// ---------------------------------------------------------------------------
// Newton-Schulz sqrtm per (b,g) 32x32 + row-mean -> s[b,c]
// ---------------------------------------------------------------------------
__device__ __forceinline__ void mm32(float (*A)[33], float (*Bm)[33],
                                     float (*O)[33], int ei, int ej0)
{
    float a0 = 0.f, a1 = 0.f, a2 = 0.f, a3 = 0.f;
#pragma unroll
    for (int k = 0; k < 32; ++k) {
        const float a = A[ei][k];
        a0 = fmaf(a, Bm[k][ej0 + 0], a0);
        a1 = fmaf(a, Bm[k][ej0 + 1], a1);
        a2 = fmaf(a, Bm[k][ej0 + 2], a2);
        a3 = fmaf(a, Bm[k][ej0 + 3], a3);
    }
    O[ei][ej0 + 0] = a0;
    O[ei][ej0 + 1] = a1;
    O[ei][ej0 + 2] = a2;
    O[ei][ej0 + 3] = a3;
    __syncthreads();
}

__launch_bounds__(256)
__global__ void sqrtm_kernel(const float* __restrict__ cov,
                             const float* __restrict__ sf,
                             float* __restrict__ sout)
{
    __shared__ float b0[32][33], b1[32][33], b2[32][33], b3[32][33];
    __shared__ float sh_tr, sh_scale;
    const int bg = blockIdx.x;
    const int b = bg >> 2, g = bg & 3;
    const int tid = threadIdx.x;
    const int ei = (tid * 4) >> 5, ej0 = (tid * 4) & 31;
    const float* cp = cov + (size_t)bg * (Dn * Dn);
    const float* fs = sf + b * Cn + g * Dn;
    const float invM = 1.f / Mn;
    const float mi = fs[ei] * invM;
#pragma unroll
    for (int q = 0; q < 4; ++q)
        b0[ei][ej0 + q] = cp[ei * Dn + ej0 + q] * invM - mi * (fs[ej0 + q] * invM);
    __syncthreads();
    if (tid < 32) {
        float d = b0[tid][tid];
#pragma unroll
        for (int dd = 1; dd < 32; dd <<= 1) d += __shfl_xor(d, dd);
        if (tid == 0) { sh_tr = d; sh_scale = 0.5f * sqrtf(d); }
    }
    __syncthreads();
    const float invtr = 1.f / sh_tr;
#pragma unroll
    for (int q = 0; q < 4; ++q) {
        const float an = b0[ei][ej0 + q] * invtr;
        b0[ei][ej0 + q] = an;
        b1[ei][ej0 + q] = ((ei == ej0 + q) ? 1.5f : 0.f) - 0.5f * an;
    }
    __syncthreads();
    mm32(b0, b1, b2, ei, ej0);  // Y = An @ ZY
    float (*pY)[33] = b2;
    float (*pZ)[33] = b1;
    float (*pF1)[33] = b0;
    float (*pF2)[33] = b3;
#pragma unroll 1
    for (int it = 0; it < 3; ++it) {
        mm32(pZ, pY, pF1, ei, ej0);
#pragma unroll
        for (int q = 0; q < 4; ++q)
            pF1[ei][ej0 + q] = ((ei == ej0 + q) ? 1.5f : 0.f) - 0.5f * pF1[ei][ej0 + q];
        __syncthreads();
        mm32(pY, pF1, pF2, ei, ej0);
        mm32(pF1, pZ, pY, ei, ej0);
        float (*oldZ)[33] = pZ;
        pZ = pY;
        pY = pF2;
        pF2 = oldZ;
    }
    mm32(pZ, pY, pF1, ei, ej0);
#pragma unroll
    for (int q = 0; q < 4; ++q)
        pF1[ei][ej0 + q] = ((ei == ej0 + q) ? 3.f : 0.f) - pF1[ei][ej0 + q];
    __syncthreads();
    mm32(pY, pF1, pF2, ei, ej0);
    if (tid < 32) {
        float t = 0.f;
#pragma unroll
        for (int i = 0; i < 32; ++i) t += pF2[i][tid];
        sout[b * Cn + g * Dn + tid] = t * sh_scale * (1.f / Dn);
    }
}

// ---------------------------------------------------------------------------
// coef1 / coef2 (analytic affine propagation)
// ---------------------------------------------------------------------------
__launch_bounds__(1024)
__global__ void coef1_kernel(const float* __restrict__ sf, const float* __restrict__ sf2,
                             const float* __restrict__ sfx, const float* __restrict__ sx,
                             const float* __restrict__ sx2, const float* __restrict__ s,
                             const float* __restrict__ gng, const float* __restrict__ gnb,
                             const float* __restrict__ bn1g, const float* __restrict__ bn1b,
                             float* __restrict__ Ay, float* __restrict__ By,
                             float* __restrict__ Ah, float* __restrict__ Bh)
{
    __shared__ float smv[Bn * Cn];
    __shared__ float sm2[Bn * Cn];
    __shared__ float smu[Bn * Gn], srs[Bn * Gn];
    __shared__ float sV[Cn];
    const int tid = threadIdx.x;
    const float invM = 1.f / Mn;
    for (int p = tid; p < Bn * Cn; p += 1024) {
        const float sv = s[p];
        smv[p] = fmaf(sv, sf[p], sx[p]) * invM;
        sm2[p] = (sv * sv * sf2[p] + 2.f * sv * sfx[p] + sx2[p]) * invM;
    }
    __syncthreads();
    if (tid < Bn * Gn) {
        const int base = tid * Dn;
        float mu = 0.f, e2 = 0.f;
        for (int c = 0; c < Dn; ++c) { mu += smv[base + c]; e2 += sm2[base + c]; }
        mu *= (1.f / Dn); e2 *= (1.f / Dn);
        smu[tid] = mu;
        srs[tid] = rsqrtf(e2 - mu * mu + GN_EPS);
    }
    __syncthreads();
    for (int p = tid; p < Bn * Cn; p += 1024) {
        const int c = p & (Cn - 1);
        const int bg = p >> 5;
        const float ay = srs[bg] * gng[c];
        const float mv = smv[p];
        sm2[p] = ay * ay * (sm2[p] - mv * mv);
    }
    __syncthreads();
    if (tid < Cn) {
        float V = 0.f;
        for (int b = 0; b < Bn; ++b) {
            const float vy = sm2[b * Cn + tid];
            V += vy / (vy + IN_EPS);
        }
        sV[tid] = V * (1.f / Bn);
    }
    __syncthreads();
    for (int p = tid; p < Bn * Cn; p += 1024) {
        const int c = p & (Cn - 1);
        const int bg = p >> 5;
        const float ay = srs[bg] * gng[c];
        const float mv = smv[p];
        const float by = gnb[c] - smu[bg] * ay;
        const float rsin = rsqrtf(sm2[p] + IN_EPS);
        const float ah = ay * rsin * rsqrtf(sV[c] + BN_EPS) * bn1g[c];
        const float bh = bn1b[c] - ah * mv;
        Ay[p] = ay; By[p] = by; Ah[p] = ah; Bh[p] = bh;
    }
}

__launch_bounds__(1024)
__global__ void coef2_kernel(const float* __restrict__ sum1, const float* __restrict__ sum2,
                             const float* __restrict__ bn2g, const float* __restrict__ bn2b,
                             float* __restrict__ A2, float* __restrict__ B2)
{
    __shared__ float svar[Bn * Cn];
    __shared__ float sV[Cn];
    const int tid = threadIdx.x;
    const float invM = 1.f / Mn;
    for (int p = tid; p < Bn * Cn; p += 1024) {
        const float mu = sum1[p] * invM;
        svar[p] = sum2[p] * invM - mu * mu;
    }
    __syncthreads();
    if (tid < Cn) {
        float V = 0.f;
        for (int b = 0; b < Bn; ++b) {
            const float v = svar[b * Cn + tid];
            V += v / (v + IN_EPS);
        }
        sV[tid] = V * (1.f / Bn);
    }
    __syncthreads();
    for (int p = tid; p < Bn * Cn; p += 1024) {
        const int c = p & (Cn - 1);
        const float mu = sum1[p] * invM;
        const float a2 = rsqrtf(svar[p] + IN_EPS) * rsqrtf(sV[c] + BN_EPS) * bn2g[c];
        A2[p] = a2;
        B2[p] = bn2b[c] - a2 * mu;
    }
}

// ---------------------------------------------------------------------------
extern "C" void kernel_launch(void* const* d_in, const int* in_sizes, int n_in,
                              void* d_out, int out_size, void* d_ws, size_t ws_size,
                              hipStream_t stream)
{
    const float* x      = (const float*)d_in[0];
    const float* w_lin  = (const float*)d_in[1];
    const float* gn_g   = (const float*)d_in[2];
    const float* gn_b   = (const float*)d_in[3];
    const float* bn1g   = (const float*)d_in[4];
    const float* bn1b   = (const float*)d_in[5];
    const float* conv1w = (const float*)d_in[6];
    const float* conv1b = (const float*)d_in[7];
    const float* bn2g   = (const float*)d_in[8];
    const float* bn2b   = (const float*)d_in[9];
    const float* conv2w = (const float*)d_in[10];
    const float* conv2b = (const float*)d_in[11];
    float* out = (float*)d_out;

    const size_t TS = (size_t)Bn * Mn * Cn;
    ushort* xt    = (ushort*)d_ws;
    ushort* featt = xt + TS;
    ushort* h2t   = featt + TS;       // [b][2][m][64] layout
    ushort* wb1   = h2t + TS;
    ushort* wb2   = wb1 + Cn * Cn;
    ushort* wb3   = wb2 + Cn * Cn;
    float*  fbase = (float*)(wb3 + Cn * Cn);
    float* sarr = fbase;
    float* Ay   = sarr + Bn * Cn;
    float* By   = Ay + Bn * Cn;
    float* Ah   = By + Bn * Cn;
    float* Bh   = Ah + Bn * Cn;
    float* A2   = Bh + Bn * Cn;
    float* B2   = A2 + Bn * Cn;
    float* zbase = B2 + Bn * Cn;
    float* cov  = zbase;
    float* sf   = cov + Bn * Gn * Dn * Dn;
    float* sf2  = sf + Bn * Cn;
    float* sfx  = sf2 + Bn * Cn;
    float* sx   = sfx + Bn * Cn;
    float* sx2  = sx + Bn * Cn;
    float* sum1 = sx2 + Bn * Cn;
    float* sum2 = sum1 + Bn * Cn;
    const size_t zfloats = (size_t)Bn * Gn * Dn * Dn + 7 * Bn * Cn;  // 159744
    const int zquads = (int)(zfloats / 4);                           // 39936

    // zeroing fused into prep_w3 (replaces slow hipMemsetAsync fill kernel)
    prep_w3<<<dim3(192), 256, 0, stream>>>(w_lin, conv1w, conv2w, wb1, zbase, zquads);
    prep_xt<<<dim3(Mn / 32, Bn), 256, 0, stream>>>(x, xt);

    // 1) FUSED: featt = xt @ W1^T + all channel stats + covariance
    mgemm0_cov<<<dim3((Mn + 255) / 256, Bn), 256, 0, stream>>>(
        wb1, xt, featt, sf, sf2, sfx, sx, sx2, cov);

    // 2) Newton-Schulz sqrtm -> s
    sqrtm_kernel<<<Bn * Gn, 256, 0, stream>>>(cov, sf, sarr);

    // 3) affine coefficients (GN + first IN/BN/ReLU)
    coef1_kernel<<<1, 1024, 0, stream>>>(sf, sf2, sfx, sx, sx2, sarr,
                                         gn_g, gn_b, bn1g, bn1b, Ay, By, Ah, Bh);

    const dim3 ggrid((Mn + 63) / 64, 2, Bn);   // 63 x 2 x 32 = 4032 blocks

    // 4) h2t = relu(Ah*(s*featt+xt)+Bh) @ W2^T + b1, stats (full-line writes)
    mgemm_kernel<1><<<ggrid, 256, 0, stream>>>(
        wb2, featt, xt, h2t, nullptr, conv1b, sarr, Ah, Bh,
        nullptr, nullptr, nullptr, nullptr, sum1, sum2);

    // 5) second-stage affine coefficients
    coef2_kernel<<<1, 1024, 0, stream>>>(sum1, sum2, bn2g, bn2b, A2, B2);

    // 6) out = relu(A2*h2t+B2) @ W3^T + b2 + y (y recomputed from featt/xt)
    mgemm_kernel<2><<<ggrid, 256, 0, stream>>>(
        wb3, h2t, nullptr, nullptr, out, conv2b, sarr, A2, B2,
        Ay, By, featt, xt, nullptr, nullptr);
}

// Round 17
// 125.847 us; speedup vs baseline: 1.1124x; 1.0932x over previous
//
#include <hip/hip_runtime.h>

constexpr int Bn = 32;
constexpr int Cn = 128;
constexpr int Mn = 4000;
constexpr int Gn = 4;
constexpr int Dn = 32;   // C / G
constexpr float GN_EPS = 1e-5f;
constexpr float IN_EPS = 1e-3f;
constexpr float BN_EPS = 1e-5f;

typedef __attribute__((ext_vector_type(8))) short bf16x8;
typedef __attribute__((ext_vector_type(4))) float f32x4;
typedef __attribute__((ext_vector_type(16))) float f32x16;

__device__ __forceinline__ float bf2f(ushort u) {
    union { unsigned int u; float f; } v;
    v.u = ((unsigned int)u) << 16;
    return v.f;
}
__device__ __forceinline__ ushort f2bf(float f) {
    union { float f; unsigned int u; } v;
    v.f = f;
    unsigned int r = v.u + 0x7FFFu + ((v.u >> 16) & 1u);
    return (ushort)(r >> 16);
}

// ---------------------------------------------------------------------------
// prep_w3: three fp32 W[128][128] -> bf16, PLUS zero the accumulator region.
// ---------------------------------------------------------------------------
__global__ void prep_w3(const float* __restrict__ w0, const float* __restrict__ w1,
                        const float* __restrict__ w2, ushort* __restrict__ wb,
                        float* __restrict__ zbase, int zquads) {
    const int i = blockIdx.x * 256 + threadIdx.x;   // 49152 total
    const int which = i >> 14;
    const int off = i & 16383;
    const float v = (which == 0) ? w0[off] : (which == 1) ? w1[off] : w2[off];
    wb[i] = f2bf(v);
    if (i < zquads) {
        f32x4 z;
        z[0] = 0.f; z[1] = 0.f; z[2] = 0.f; z[3] = 0.f;
        *(f32x4*)(zbase + (size_t)i * 4) = z;
    }
}

// ---------------------------------------------------------------------------
// prep_xt: x [b][c][m] fp32 -> xt [b][m][c] bf16.
// ---------------------------------------------------------------------------
__launch_bounds__(256)
__global__ void prep_xt(const float* __restrict__ x, ushort* __restrict__ xt) {
    __shared__ float tl[128 * 33];   // [c][m], 16896 B
    const int mb = blockIdx.x * 32, b = blockIdx.y;
    const int tid = threadIdx.x;
    const int mi = tid & 31, cg = tid >> 5;
#pragma unroll
    for (int p = 0; p < 16; ++p) {
        const int ci = cg + 8 * p;                  // 0..127
        tl[ci * 33 + mi] = x[((size_t)b * Cn + ci) * Mn + mb + mi];
    }
    __syncthreads();
#pragma unroll
    for (int q = 0; q < 2; ++q) {
        const int row = (tid >> 4) + 16 * q;        // 0..31
        const int c8 = (tid & 15) * 8;
        bf16x8 v;
#pragma unroll
        for (int e = 0; e < 8; ++e)
            v[e] = (short)f2bf(tl[(c8 + e) * 33 + row]);
        *(bf16x8*)(xt + ((size_t)b * Mn + mb + row) * Cn + c8) = v;
    }
}

// ---------------------------------------------------------------------------
// FUSED M0 + covariance + ALL channel stats, 4 m-tiles per block.
// ---------------------------------------------------------------------------
constexpr int WPAD = 136;   // ushort stride for W rows
constexpr int EP0  = 132;   // ushort stride for El tile

__launch_bounds__(256, 2)
__global__ void mgemm0_cov(const ushort* __restrict__ Wb,
                           const ushort* __restrict__ src,      // xt
                           ushort* __restrict__ dst_bf,         // featt
                           float* __restrict__ sf, float* __restrict__ sf2,
                           float* __restrict__ sfxp,
                           float* __restrict__ sxp, float* __restrict__ sx2p,
                           float* __restrict__ covp)
{
    __shared__ ushort Wl[128 * WPAD];   // W, persists across tiles
    __shared__ ushort El[64 * EP0];     // featt tile; red aliases after loop
    const int b = blockIdx.y;
    const int mb0 = blockIdx.x * 256;
    const int tid = threadIdx.x;
    const int wv = tid >> 6, l = tid & 63;
    const int li = l & 15, lg = l >> 4;

#pragma unroll
    for (int p = 0; p < 8; ++p) {
        const int u = tid + 256 * p;
        const int o = u >> 4, c8 = (u & 15) * 8;
        *(bf16x8*)&Wl[o * WPAD + c8] = *(const bf16x8*)(Wb + (size_t)o * 128 + c8);
    }
    __syncthreads();

    f32x16 cacc;
#pragma unroll
    for (int i = 0; i < 16; ++i) cacc[i] = 0.f;
    float s1a[8] = {}, s2a[8] = {}, s3a[8] = {}, s4a[8] = {}, s5a[8] = {};

    const int c8s = (tid & 15) * 8;
    const int cg = wv * 32 + (l & 31);
    const int kb8 = (l >> 5) * 8;

#pragma unroll 1
    for (int t = 0; t < 4; ++t) {
        const int mb = mb0 + t * 64;
        const int ma = mb + wv * 16 + li;
        const bool mok = ma < Mn;
        const size_t qrow = ((size_t)b * Mn + (mok ? ma : (Mn - 1))) * Cn;

        bf16x8 fr[4];
#pragma unroll
        for (int kb = 0; kb < 4; ++kb)
            fr[kb] = *(const bf16x8*)(src + qrow + kb * 32 + 8 * lg);

        f32x4 acc[8];
#pragma unroll
        for (int j = 0; j < 8; ++j)
#pragma unroll
            for (int r = 0; r < 4; ++r) acc[j][r] = 0.f;

#pragma unroll
        for (int kb = 0; kb < 4; ++kb) {
            const int cl = kb * 32 + 8 * lg;
#pragma unroll
            for (int j = 0; j < 8; ++j) {
                const bf16x8 bj = *(const bf16x8*)&Wl[(j * 16 + li) * WPAD + cl];
                acc[j] = __builtin_amdgcn_mfma_f32_16x16x32_bf16(fr[kb], bj, acc[j], 0, 0, 0);
            }
        }

        __syncthreads();
#pragma unroll
        for (int j = 0; j < 8; ++j) {
            const int o = j * 16 + li;
#pragma unroll
            for (int r = 0; r < 4; ++r) {
                const int ml = wv * 16 + lg * 4 + r;
                El[ml * EP0 + o] = (mb + ml < Mn) ? f2bf(acc[j][r]) : (ushort)0;
            }
        }
        __syncthreads();

#pragma unroll
        for (int p = 0; p < 4; ++p) {
            const int row = (tid >> 4) + 16 * p;
            const int m = mb + row;
            const bf16x8 v8 = *(const bf16x8*)&El[row * EP0 + c8s];
            if (m < Mn) {
                const size_t q = ((size_t)b * Mn + m) * Cn + c8s;
                *(bf16x8*)(dst_bf + q) = v8;
                const bf16x8 x8 = *(const bf16x8*)(src + q);
#pragma unroll
                for (int e = 0; e < 8; ++e) {
                    const float f = bf2f((ushort)v8[e]);
                    const float xv = bf2f((ushort)x8[e]);
                    s1a[e] += f;
                    s2a[e] = fmaf(f, f, s2a[e]);
                    s3a[e] = fmaf(f, xv, s3a[e]);
                    s4a[e] += xv;
                    s5a[e] = fmaf(xv, xv, s5a[e]);
                }
            }
        }

#pragma unroll
        for (int ks = 0; ks < 4; ++ks) {
            bf16x8 fgr;
#pragma unroll
            for (int e = 0; e < 8; ++e)
                fgr[e] = (short)El[(ks * 16 + kb8 + e) * EP0 + cg];
            cacc = __builtin_amdgcn_mfma_f32_32x32x16_bf16(fgr, fgr, cacc, 0, 0, 0);
        }
    }

    __syncthreads();
#pragma unroll
    for (int e = 0; e < 8; ++e) {
        s1a[e] += __shfl_xor(s1a[e], 16); s1a[e] += __shfl_xor(s1a[e], 32);
        s2a[e] += __shfl_xor(s2a[e], 16); s2a[e] += __shfl_xor(s2a[e], 32);
        s3a[e] += __shfl_xor(s3a[e], 16); s3a[e] += __shfl_xor(s3a[e], 32);
        s4a[e] += __shfl_xor(s4a[e], 16); s4a[e] += __shfl_xor(s4a[e], 32);
        s5a[e] += __shfl_xor(s5a[e], 16); s5a[e] += __shfl_xor(s5a[e], 32);
    }
    float* red = (float*)El;
    if (l < 16) {
#pragma unroll
        for (int e = 0; e < 8; ++e) {
            red[(wv * 16 + l) * 40 + e]      = s1a[e];
            red[(wv * 16 + l) * 40 + 8 + e]  = s2a[e];
            red[(wv * 16 + l) * 40 + 16 + e] = s3a[e];
            red[(wv * 16 + l) * 40 + 24 + e] = s4a[e];
            red[(wv * 16 + l) * 40 + 32 + e] = s5a[e];
        }
    }
    __syncthreads();
    if (tid < 128) {
        const int oc = tid >> 3, e = tid & 7;
        const int o = oc * 8 + e;
        float t1 = 0.f, t2 = 0.f, t3 = 0.f, t4 = 0.f, t5 = 0.f;
#pragma unroll
        for (int w = 0; w < 4; ++w) {
            t1 += red[(w * 16 + oc) * 40 + e];
            t2 += red[(w * 16 + oc) * 40 + 8 + e];
            t3 += red[(w * 16 + oc) * 40 + 16 + e];
            t4 += red[(w * 16 + oc) * 40 + 24 + e];
            t5 += red[(w * 16 + oc) * 40 + 32 + e];
        }
        atomicAdd(&sf[b * Cn + o], t1);
        atomicAdd(&sf2[b * Cn + o], t2);
        atomicAdd(&sfxp[b * Cn + o], t3);
        atomicAdd(&sxp[b * Cn + o], t4);
        atomicAdd(&sx2p[b * Cn + o], t5);
    }
    float* cvb = covp + (size_t)(b * Gn + wv) * (Dn * Dn);
#pragma unroll
    for (int reg = 0; reg < 16; ++reg) {
        const int i = (reg & 3) + 8 * (reg >> 2) + 4 * (l >> 5);
        const int j = l & 31;
        atomicAdd(&cvb[i * Dn + j], cacc[reg]);
    }
}

// ---------------------------------------------------------------------------
// MFMA GEMM for MODE 1/2: 4 m-tiles per block (256m x 64o), o-split grid.
// Amortizes W/coef staging + epilogue fixed costs over 4 tiles; stats
// accumulate in registers and flush once per block.
// grid ((Mn+255)/256, 2, Bn) = (16, 2, 32) = 1024 blocks.
// LDS: Wl 17408 + El 8704 + coef 2560 = 28672 B -> 5 blocks/CU.
// ---------------------------------------------------------------------------
constexpr int EPAD = 68;    // ushort stride for 64-wide epilogue tiles

template <int MODE>
__launch_bounds__(256, 5)
__global__ void mgemm_kernel(const ushort* __restrict__ Wb,
                             const ushort* __restrict__ src,
                             const ushort* __restrict__ xsrc,
                             ushort* __restrict__ dst_bf,
                             float* __restrict__ dst_f32,
                             const float* __restrict__ bias,
                             const float* __restrict__ sarr,
                             const float* __restrict__ tA,
                             const float* __restrict__ tB,
                             const float* __restrict__ Ayc,
                             const float* __restrict__ Byc,
                             const ushort* __restrict__ yfeat,
                             const ushort* __restrict__ yxt,
                             float* __restrict__ sum1,
                             float* __restrict__ sum2)
{
    __shared__ ushort Wl[64 * WPAD];      // 17408 B, persists across tiles
    __shared__ ushort El[64 * EPAD];      // 8704 B; M2's TR aliases this
    __shared__ float coefLDS[640];
    const int b = blockIdx.z;
    const int obh = blockIdx.y;           // o-half index
    const int ob = obh * 64;
    const int mb0 = blockIdx.x * 256;
    const int tid = threadIdx.x;
    const int wv = tid >> 6, l = tid & 63;
    const int li = l & 15, lg = l >> 4;

#pragma unroll
    for (int p = 0; p < 4; ++p) {
        const int u = tid + 256 * p;
        const int row = u >> 4, c8 = (u & 15) * 8;
        *(bf16x8*)&Wl[row * WPAD + c8] = *(const bf16x8*)(Wb + (size_t)(ob + row) * 128 + c8);
    }
    {
        const int ncoef = (MODE == 1) ? 384 : 640;
        for (int idx = tid; idx < ncoef; idx += 256) {
            const int arr = idx >> 7, c = idx & 127;
            float v;
            switch (arr) {
                case 0: v = tA[b * Cn + c]; break;
                case 1: v = tB[b * Cn + c]; break;
                case 2: v = sarr[b * Cn + c]; break;
                case 3: v = Ayc[b * Cn + c]; break;
                default: v = Byc[b * Cn + c]; break;
            }
            coefLDS[idx] = v;
        }
    }
    __syncthreads();

    float s1a[8] = {}, s2a[8] = {};       // MODE 1 stats, across tiles
    const int c8l = (tid & 7) * 8;

#pragma unroll 1
    for (int t = 0; t < 4; ++t) {
        const int mb = mb0 + t * 64;
        const int ma = mb + wv * 16 + li;
        const bool mok = ma < Mn;
        const int mc = mok ? ma : (Mn - 1);
        const size_t qrow = ((size_t)b * Mn + mc) * Cn;

        bf16x8 fr[4], xr[4];
#pragma unroll
        for (int kb = 0; kb < 4; ++kb) {
            if (MODE == 1) {
                const int cl = kb * 32 + 8 * lg;
                fr[kb] = *(const bf16x8*)(src + qrow + cl);
                xr[kb] = *(const bf16x8*)(xsrc + qrow + cl);
            } else {
                const size_t q2 = (((size_t)b * 2 + (kb >> 1)) * Mn + mc) * 64 + (kb & 1) * 32 + 8 * lg;
                fr[kb] = *(const bf16x8*)(src + q2);
            }
        }

        f32x4 acc[4];
#pragma unroll
        for (int j = 0; j < 4; ++j)
#pragma unroll
            for (int r = 0; r < 4; ++r) acc[j][r] = 0.f;

#pragma unroll
        for (int kb = 0; kb < 4; ++kb) {
            const int cl = kb * 32 + 8 * lg;
            bf16x8 af;
            if (MODE == 1) {
                const float4 a0 = *(const float4*)&coefLDS[0 + cl];
                const float4 a1 = *(const float4*)&coefLDS[0 + cl + 4];
                const float4 b0 = *(const float4*)&coefLDS[128 + cl];
                const float4 b1 = *(const float4*)&coefLDS[128 + cl + 4];
                const float4 s0 = *(const float4*)&coefLDS[256 + cl];
                const float4 s1 = *(const float4*)&coefLDS[256 + cl + 4];
                const float tAv[8] = {a0.x,a0.y,a0.z,a0.w,a1.x,a1.y,a1.z,a1.w};
                const float tBv[8] = {b0.x,b0.y,b0.z,b0.w,b1.x,b1.y,b1.z,b1.w};
                const float svv[8] = {s0.x,s0.y,s0.z,s0.w,s1.x,s1.y,s1.z,s1.w};
#pragma unroll
                for (int e = 0; e < 8; ++e) {
                    const float vv = fmaf(svv[e], bf2f((ushort)fr[kb][e]), bf2f((ushort)xr[kb][e]));
                    af[e] = (short)f2bf(fmaxf(fmaf(tAv[e], vv, tBv[e]), 0.f));
                }
            } else {
                const float4 a0 = *(const float4*)&coefLDS[0 + cl];
                const float4 a1 = *(const float4*)&coefLDS[0 + cl + 4];
                const float4 b0 = *(const float4*)&coefLDS[128 + cl];
                const float4 b1 = *(const float4*)&coefLDS[128 + cl + 4];
                const float tAv[8] = {a0.x,a0.y,a0.z,a0.w,a1.x,a1.y,a1.z,a1.w};
                const float tBv[8] = {b0.x,b0.y,b0.z,b0.w,b1.x,b1.y,b1.z,b1.w};
#pragma unroll
                for (int e = 0; e < 8; ++e)
                    af[e] = (short)f2bf(fmaxf(fmaf(tAv[e], bf2f((ushort)fr[kb][e]), tBv[e]), 0.f));
            }
#pragma unroll
            for (int j = 0; j < 4; ++j) {
                const bf16x8 bj = *(const bf16x8*)&Wl[(j * 16 + li) * WPAD + cl];
                acc[j] = __builtin_amdgcn_mfma_f32_16x16x32_bf16(af, bj, acc[j], 0, 0, 0);
            }
        }

        // -------- per-tile epilogue --------
        if (MODE == 1) {
            __syncthreads();   // prev tile's El reads done
#pragma unroll
            for (int j = 0; j < 4; ++j) {
                const int o = j * 16 + li;
                const float bv = bias[ob + o];
#pragma unroll
                for (int r = 0; r < 4; ++r) {
                    const int ml = wv * 16 + lg * 4 + r;
                    El[ml * EPAD + o] = f2bf(acc[j][r] + bv);
                }
            }
            __syncthreads();
#pragma unroll
            for (int p = 0; p < 2; ++p) {
                const int row = (tid >> 3) + 32 * p;
                const int m = mb + row;
                const bf16x8 v8 = *(const bf16x8*)&El[row * EPAD + c8l];
                if (m < Mn) {
                    *(bf16x8*)(dst_bf + (((size_t)b * 2 + obh) * Mn + m) * 64 + c8l) = v8;
#pragma unroll
                    for (int e = 0; e < 8; ++e) {
                        const float f = bf2f((ushort)v8[e]);
                        s1a[e] += f;
                        s2a[e] = fmaf(f, f, s2a[e]);
                    }
                }
            }
        } else {
            __syncthreads();   // prev tile's El/TR use done
            float* TR = (float*)El;
#pragma unroll
            for (int p = 0; p < 2; ++p) {
                const int row = (tid >> 3) + 32 * p;
                bf16x8 yv;
#pragma unroll
                for (int e = 0; e < 8; ++e) yv[e] = 0;
                if (mb + row < Mn) {
                    const size_t q = ((size_t)b * Mn + mb + row) * Cn + ob + c8l;
                    const bf16x8 f8 = *(const bf16x8*)(yfeat + q);
                    const bf16x8 x8 = *(const bf16x8*)(yxt + q);
#pragma unroll
                    for (int e = 0; e < 8; ++e) {
                        const int c = ob + c8l + e;
                        const float vv = fmaf(coefLDS[256 + c], bf2f((ushort)f8[e]), bf2f((ushort)x8[e]));
                        yv[e] = (short)f2bf(fmaf(coefLDS[384 + c], vv, coefLDS[512 + c]));
                    }
                }
                *(bf16x8*)&El[row * EPAD + c8l] = yv;
            }
            __syncthreads();
#pragma unroll
            for (int j = 0; j < 4; ++j) {
                const int o = j * 16 + li;
                const float bv = bias[ob + o];
#pragma unroll
                for (int r = 0; r < 4; ++r) {
                    const int ml = wv * 16 + lg * 4 + r;
                    acc[j][r] += bv + bf2f(El[ml * EPAD + o]);
                }
            }
#pragma unroll
            for (int h = 0; h < 2; ++h) {
                __syncthreads();   // El reads (h=0) / prev stores (h=1) done
#pragma unroll
                for (int jj = 0; jj < 2; ++jj) {
                    const int j = h * 2 + jj;
#pragma unroll
                    for (int r = 0; r < 4; ++r) {
                        const int ml = wv * 16 + lg * 4 + r;
                        TR[(jj * 16 + li) * EPAD + ml] = acc[j][r];
                    }
                }
                __syncthreads();
#pragma unroll
                for (int p = 0; p < 2; ++p) {
                    const int u = tid + 256 * p;
                    const int ol = u >> 4, q = u & 15;
                    const int m = mb + 4 * q;
                    if (m < Mn) {
                        const f32x4 v = *(const f32x4*)&TR[ol * EPAD + 4 * q];
                        *(f32x4*)(dst_f32 + ((size_t)b * Cn + ob + h * 32 + ol) * Mn + m) = v;
                    }
                }
            }
        }
    }

    // -------- MODE 1: flush stats once per block --------
    if constexpr (MODE == 1) {
#pragma unroll
        for (int e = 0; e < 8; ++e) {
            s1a[e] += __shfl_xor(s1a[e], 8);  s2a[e] += __shfl_xor(s2a[e], 8);
            s1a[e] += __shfl_xor(s1a[e], 16); s2a[e] += __shfl_xor(s2a[e], 16);
            s1a[e] += __shfl_xor(s1a[e], 32); s2a[e] += __shfl_xor(s2a[e], 32);
        }
        __syncthreads();
        float* red = coefLDS;
        if (l < 8) {
#pragma unroll
            for (int e = 0; e < 8; ++e) {
                red[wv * 128 + l * 8 + e] = s1a[e];
                red[wv * 128 + 64 + l * 8 + e] = s2a[e];
            }
        }
        __syncthreads();
        if (tid < 128) {
            const int which = tid >> 6, ol = tid & 63;
            const float v = red[0 * 128 + which * 64 + ol] + red[1 * 128 + which * 64 + ol] +
                            red[2 * 128 + which * 64 + ol] + red[3 * 128 + which * 64 + ol];
            atomicAdd((which ? sum2 : sum1) + b * Cn + ob + ol, v);
        }
    }
}

// ---------------------------------------------------------------------------
// Newton-Schulz sqrtm per (b,g) 32x32 + row-mean -> s[b,c]
// ---------------------------------------------------------------------------
__device__ __forceinline__ void mm32(float (*A)[33], float (*Bm)[33],
                                     float (*O)[33], int ei, int ej0)
{
    float a0 = 0.f, a1 = 0.f, a2 = 0.f, a3 = 0.f;
#pragma unroll
    for (int k = 0; k < 32; ++k) {
        const float a = A[ei][k];
        a0 = fmaf(a, Bm[k][ej0 + 0], a0);
        a1 = fmaf(a, Bm[k][ej0 + 1], a1);
        a2 = fmaf(a, Bm[k][ej0 + 2], a2);
        a3 = fmaf(a, Bm[k][ej0 + 3], a3);
    }
    O[ei][ej0 + 0] = a0;
    O[ei][ej0 + 1] = a1;
    O[ei][ej0 + 2] = a2;
    O[ei][ej0 + 3] = a3;
    __syncthreads();
}

__launch_bounds__(256)
__global__ void sqrtm_kernel(const float* __restrict__ cov,
                             const float* __restrict__ sf,
                             float* __restrict__ sout)
{
    __shared__ float b0[32][33], b1[32][33], b2[32][33], b3[32][33];
    __shared__ float sh_tr, sh_scale;
    const int bg = blockIdx.x;
    const int b = bg >> 2, g = bg & 3;
    const int tid = threadIdx.x;
    const int ei = (tid * 4) >> 5, ej0 = (tid * 4) & 31;
    const float* cp = cov + (size_t)bg * (Dn * Dn);
    const float* fs = sf + b * Cn + g * Dn;
    const float invM = 1.f / Mn;
    const float mi = fs[ei] * invM;
#pragma unroll
    for (int q = 0; q < 4; ++q)
        b0[ei][ej0 + q] = cp[ei * Dn + ej0 + q] * invM - mi * (fs[ej0 + q] * invM);
    __syncthreads();
    if (tid < 32) {
        float d = b0[tid][tid];
#pragma unroll
        for (int dd = 1; dd < 32; dd <<= 1) d += __shfl_xor(d, dd);
        if (tid == 0) { sh_tr = d; sh_scale = 0.5f * sqrtf(d); }
    }
    __syncthreads();
    const float invtr = 1.f / sh_tr;
#pragma unroll
    for (int q = 0; q < 4; ++q) {
        const float an = b0[ei][ej0 + q] * invtr;
        b0[ei][ej0 + q] = an;
        b1[ei][ej0 + q] = ((ei == ej0 + q) ? 1.5f : 0.f) - 0.5f * an;
    }
    __syncthreads();
    mm32(b0, b1, b2, ei, ej0);  // Y = An @ ZY
    float (*pY)[33] = b2;
    float (*pZ)[33] = b1;
    float (*pF1)[33] = b0;
    float (*pF2)[33] = b3;
#pragma unroll 1
    for (int it = 0; it < 3; ++it) {
        mm32(pZ, pY, pF1, ei, ej0);
#pragma unroll
        for (int q = 0; q < 4; ++q)
            pF1[ei][ej0 + q] = ((ei == ej0 + q) ? 1.5f : 0.f) - 0.5f * pF1[ei][ej0 + q];
        __syncthreads();
        mm32(pY, pF1, pF2, ei, ej0);
        mm32(pF1, pZ, pY, ei, ej0);
        float (*oldZ)[33] = pZ;
        pZ = pY;
        pY = pF2;
        pF2 = oldZ;
    }
    mm32(pZ, pY, pF1, ei, ej0);
#pragma unroll
    for (int q = 0; q < 4; ++q)
        pF1[ei][ej0 + q] = ((ei == ej0 + q) ? 3.f : 0.f) - pF1[ei][ej0 + q];
    __syncthreads();
    mm32(pY, pF1, pF2, ei, ej0);
    if (tid < 32) {
        float t = 0.f;
#pragma unroll
        for (int i = 0; i < 32; ++i) t += pF2[i][tid];
        sout[b * Cn + g * Dn + tid] = t * sh_scale * (1.f / Dn);
    }
}

// ---------------------------------------------------------------------------
// coef1 / coef2 (analytic affine propagation)
// ---------------------------------------------------------------------------
__launch_bounds__(1024)
__global__ void coef1_kernel(const float* __restrict__ sf, const float* __restrict__ sf2,
                             const float* __restrict__ sfx, const float* __restrict__ sx,
                             const float* __restrict__ sx2, const float* __restrict__ s,
                             const float* __restrict__ gng, const float* __restrict__ gnb,
                             const float* __restrict__ bn1g, const float* __restrict__ bn1b,
                             float* __restrict__ Ay, float* __restrict__ By,
                             float* __restrict__ Ah, float* __restrict__ Bh)
{
    __shared__ float smv[Bn * Cn];
    __shared__ float sm2[Bn * Cn];
    __shared__ float smu[Bn * Gn], srs[Bn * Gn];
    __shared__ float sV[Cn];
    const int tid = threadIdx.x;
    const float invM = 1.f / Mn;
    for (int p = tid; p < Bn * Cn; p += 1024) {
        const float sv = s[p];
        smv[p] = fmaf(sv, sf[p], sx[p]) * invM;
        sm2[p] = (sv * sv * sf2[p] + 2.f * sv * sfx[p] + sx2[p]) * invM;
    }
    __syncthreads();
    if (tid < Bn * Gn) {
        const int base = tid * Dn;
        float mu = 0.f, e2 = 0.f;
        for (int c = 0; c < Dn; ++c) { mu += smv[base + c]; e2 += sm2[base + c]; }
        mu *= (1.f / Dn); e2 *= (1.f / Dn);
        smu[tid] = mu;
        srs[tid] = rsqrtf(e2 - mu * mu + GN_EPS);
    }
    __syncthreads();
    for (int p = tid; p < Bn * Cn; p += 1024) {
        const int c = p & (Cn - 1);
        const int bg = p >> 5;
        const float ay = srs[bg] * gng[c];
        const float mv = smv[p];
        sm2[p] = ay * ay * (sm2[p] - mv * mv);
    }
    __syncthreads();
    if (tid < Cn) {
        float V = 0.f;
        for (int b = 0; b < Bn; ++b) {
            const float vy = sm2[b * Cn + tid];
            V += vy / (vy + IN_EPS);
        }
        sV[tid] = V * (1.f / Bn);
    }
    __syncthreads();
    for (int p = tid; p < Bn * Cn; p += 1024) {
        const int c = p & (Cn - 1);
        const int bg = p >> 5;
        const float ay = srs[bg] * gng[c];
        const float mv = smv[p];
        const float by = gnb[c] - smu[bg] * ay;
        const float rsin = rsqrtf(sm2[p] + IN_EPS);
        const float ah = ay * rsin * rsqrtf(sV[c] + BN_EPS) * bn1g[c];
        const float bh = bn1b[c] - ah * mv;
        Ay[p] = ay; By[p] = by; Ah[p] = ah; Bh[p] = bh;
    }
}

__launch_bounds__(1024)
__global__ void coef2_kernel(const float* __restrict__ sum1, const float* __restrict__ sum2,
                             const float* __restrict__ bn2g, const float* __restrict__ bn2b,
                             float* __restrict__ A2, float* __restrict__ B2)
{
    __shared__ float svar[Bn * Cn];
    __shared__ float sV[Cn];
    const int tid = threadIdx.x;
    const float invM = 1.f / Mn;
    for (int p = tid; p < Bn * Cn; p += 1024) {
        const float mu = sum1[p] * invM;
        svar[p] = sum2[p] * invM - mu * mu;
    }
    __syncthreads();
    if (tid < Cn) {
        float V = 0.f;
        for (int b = 0; b < Bn; ++b) {
            const float v = svar[b * Cn + tid];
            V += v / (v + IN_EPS);
        }
        sV[tid] = V * (1.f / Bn);
    }
    __syncthreads();
    for (int p = tid; p < Bn * Cn; p += 1024) {
        const int c = p & (Cn - 1);
        const float mu = sum1[p] * invM;
        const float a2 = rsqrtf(svar[p] + IN_EPS) * rsqrtf(sV[c] + BN_EPS) * bn2g[c];
        A2[p] = a2;
        B2[p] = bn2b[c] - a2 * mu;
    }
}

// ---------------------------------------------------------------------------
extern "C" void kernel_launch(void* const* d_in, const int* in_sizes, int n_in,
                              void* d_out, int out_size, void* d_ws, size_t ws_size,
                              hipStream_t stream)
{
    const float* x      = (const float*)d_in[0];
    const float* w_lin  = (const float*)d_in[1];
    const float* gn_g   = (const float*)d_in[2];
    const float* gn_b   = (const float*)d_in[3];
    const float* bn1g   = (const float*)d_in[4];
    const float* bn1b   = (const float*)d_in[5];
    const float* conv1w = (const float*)d_in[6];
    const float* conv1b = (const float*)d_in[7];
    const float* bn2g   = (const float*)d_in[8];
    const float* bn2b   = (const float*)d_in[9];
    const float* conv2w = (const float*)d_in[10];
    const float* conv2b = (const float*)d_in[11];
    float* out = (float*)d_out;

    const size_t TS = (size_t)Bn * Mn * Cn;
    ushort* xt    = (ushort*)d_ws;
    ushort* featt = xt + TS;
    ushort* h2t   = featt + TS;       // [b][2][m][64] layout
    ushort* wb1   = h2t + TS;
    ushort* wb2   = wb1 + Cn * Cn;
    ushort* wb3   = wb2 + Cn * Cn;
    float*  fbase = (float*)(wb3 + Cn * Cn);
    float* sarr = fbase;
    float* Ay   = sarr + Bn * Cn;
    float* By   = Ay + Bn * Cn;
    float* Ah   = By + Bn * Cn;
    float* Bh   = Ah + Bn * Cn;
    float* A2   = Bh + Bn * Cn;
    float* B2   = A2 + Bn * Cn;
    float* zbase = B2 + Bn * Cn;
    float* cov  = zbase;
    float* sf   = cov + Bn * Gn * Dn * Dn;
    float* sf2  = sf + Bn * Cn;
    float* sfx  = sf2 + Bn * Cn;
    float* sx   = sfx + Bn * Cn;
    float* sx2  = sx + Bn * Cn;
    float* sum1 = sx2 + Bn * Cn;
    float* sum2 = sum1 + Bn * Cn;
    const size_t zfloats = (size_t)Bn * Gn * Dn * Dn + 7 * Bn * Cn;  // 159744
    const int zquads = (int)(zfloats / 4);                           // 39936

    prep_w3<<<dim3(192), 256, 0, stream>>>(w_lin, conv1w, conv2w, wb1, zbase, zquads);
    prep_xt<<<dim3(Mn / 32, Bn), 256, 0, stream>>>(x, xt);

    // 1) FUSED: featt = xt @ W1^T + all channel stats + covariance
    mgemm0_cov<<<dim3((Mn + 255) / 256, Bn), 256, 0, stream>>>(
        wb1, xt, featt, sf, sf2, sfx, sx, sx2, cov);

    // 2) Newton-Schulz sqrtm -> s
    sqrtm_kernel<<<Bn * Gn, 256, 0, stream>>>(cov, sf, sarr);

    // 3) affine coefficients (GN + first IN/BN/ReLU)
    coef1_kernel<<<1, 1024, 0, stream>>>(sf, sf2, sfx, sx, sx2, sarr,
                                         gn_g, gn_b, bn1g, bn1b, Ay, By, Ah, Bh);

    const dim3 ggrid((Mn + 255) / 256, 2, Bn);   // 16 x 2 x 32 = 1024 blocks

    // 4) h2t = relu(Ah*(s*featt+xt)+Bh) @ W2^T + b1, stats (4 m-tiles/block)
    mgemm_kernel<1><<<ggrid, 256, 0, stream>>>(
        wb2, featt, xt, h2t, nullptr, conv1b, sarr, Ah, Bh,
        nullptr, nullptr, nullptr, nullptr, sum1, sum2);

    // 5) second-stage affine coefficients
    coef2_kernel<<<1, 1024, 0, stream>>>(sum1, sum2, bn2g, bn2b, A2, B2);

    // 6) out = relu(A2*h2t+B2) @ W3^T + b2 + y (4 m-tiles/block)
    mgemm_kernel<2><<<ggrid, 256, 0, stream>>>(
        wb3, h2t, nullptr, nullptr, out, conv2b, sarr, A2, B2,
        Ay, By, featt, xt, nullptr, nullptr);
}